// Round 5
// baseline (296.108 us; speedup 1.0000x reference)
//
#include <hip/hip_runtime.h>
#include <utility>

typedef float v2f __attribute__((ext_vector_type(2)));

#define HDT 0.05f      // dt/2
#define KSTEPS 5       // Horner order: worst-case rel err 0.33^6 ~ 1.3e-3 << bf16 ULP

__device__ __forceinline__ float bf2f(unsigned int u) {
    return __uint_as_float(u << 16);
}
__device__ __forceinline__ unsigned int f2bf(float x) {
    unsigned int b = __float_as_uint(x);
    return (b + 0x7FFFu + ((b >> 16) & 1u)) >> 16;   // RNE
}
__device__ __forceinline__ float rfl(float x) {
    return __int_as_float(__builtin_amdgcn_readfirstlane(__float_as_int(x)));
}

// compile-time for: f(integral_constant<int,I>) for I in [0,N)
template <int... Is, class F>
__device__ __forceinline__ void static_for_impl(std::integer_sequence<int, Is...>, F&& f) {
    (f(std::integral_constant<int, Is>{}), ...);
}
template <int N, class F>
__device__ __forceinline__ void static_for(F&& f) {
    static_for_impl(std::make_integer_sequence<int, N>{}, (F&&)f);
}

// stencil coefficient slot for signed distance d (compile-time)
__host__ __device__ constexpr int cidx(int d) {
    int a = d < 0 ? -d : d;
    return (a==0)?0:(a==1)?1:(a==2)?2:(a==3)?3:(a==4)?4:(a==5)?5:(a==6)?6:
           (a==8)?7:(a==10)?8:(a==12)?9:(a==16)?10:(a==20)?11:-1;
}

// Transposed LDS layout (round-4, measured zero bank conflicts):
// quad qd lives at lds4[(qd&7)*64 + (qd>>3)] (+512 per system).
//  - own quads (qd=8L+k): row=L, sub=k -> write base L, compile-time offset
//  - window quad g (qd=8L-10+g): row=(L+c)&63, sub=(g+6)&7, 4 row regs only
__host__ __device__ constexpr int gslot(int g) {   // g -> row-register slot
    return (g < 2) ? 0 : (g < 10) ? 1 : (g < 26) ? 2 : 3;   // c = -2,-1,+1,+2
}
__host__ __device__ constexpr int gsub(int g) { return (g + 6) & 7; }

// One wave == one block == TWO systems (ILP: residency is pinned at ~2.3
// waves/SIMD regardless of config [rounds 0-4], so parallelism must live
// inside the wave). The two stencils are merged at tap granularity so each
// LDS-read latency is covered by the other system's independent FMA stream.
// (64,2): VGPR cap 256 = 2 waves/SIMD, matching observed residency.
__global__ __launch_bounds__(64, 2)
void cayley_main(const void* __restrict__ psi_r, const void* __restrict__ psi_i,
                 const void* __restrict__ alpha, const void* __restrict__ ham_w,
                 void* __restrict__ out)
{
    // 2 systems/block * 512 quads (float4 = 2 complex pts) = 16 KB
    __shared__ float4 lds4[1024];

    const int lane = threadIdx.x;          // 0..63
    const int sysA = blockIdx.x << 1;      // [0, 16384) step 2

    // ---- inline dtype probe: bf16 data's low-16 bits look like bf16 ----
    unsigned int w0 = ((const unsigned int*)psi_r)[lane];
    unsigned int ex = (w0 >> 7) & 0xFFu;
    unsigned long long bm = __ballot(ex >= 0x78u && ex <= 0x82u);
    const bool isbf = __builtin_popcountll(bm) > 32;

    // ---- combined stencil coefficients (h-scaled), forced to SGPR ----
    float hw[15];
    if (isbf) {
        const unsigned short* p = (const unsigned short*)ham_w;
        #pragma unroll
        for (int i = 0; i < 15; ++i) hw[i] = bf2f((unsigned int)p[i]);
    } else {
        const float* p = (const float*)ham_w;
        #pragma unroll
        for (int i = 0; i < 15; ++i) hw[i] = p[i];
    }
    float cs[12];
    {
        float s = 0.f;
        #pragma unroll
        for (int i = 0; i < 15; ++i) s += hw[i];
        cs[0]  = rfl( 2.f*HDT*s);                       // center
        cs[1]  = rfl(-HDT* hw[0]);                      // off 1
        cs[2]  = rfl(-HDT*(hw[1]+hw[5]));               // off 2
        cs[3]  = rfl(-HDT* hw[2]);                      // off 3
        cs[4]  = rfl(-HDT*(hw[3]+hw[6]+hw[10]));        // off 4
        cs[5]  = rfl(-HDT* hw[4]);                      // off 5
        cs[6]  = rfl(-HDT* hw[7]);                      // off 6
        cs[7]  = rfl(-HDT*(hw[8]+hw[11]));              // off 8
        cs[8]  = rfl(-HDT* hw[9]);                      // off 10
        cs[9]  = rfl(-HDT* hw[12]);                     // off 12
        cs[10] = rfl(-HDT* hw[13]);                     // off 16
        cs[11] = rfl(-HDT* hw[14]);                     // off 20
    }

    // ---- row registers for the transposed LDS layout ----
    int rw[4];
    rw[0] = (lane - 2) & 63;   // c = -2  (g 0..1)
    rw[1] = (lane - 1) & 63;   // c = -1  (g 2..9)
    rw[2] = (lane + 1) & 63;   // c = +1  (g 18..25)
    rw[3] = (lane + 2) & 63;   // c = +2  (g 26..27)

    v2f t[2][16], b[2][16], acc[2][16];

    auto ldswrite = [&](auto sI) {   // write t[s] to system-s LDS half
        constexpr int s = sI.value;
        static_for<8>([&](auto kI) {
            constexpr int k8 = kI.value;
            lds4[s*512 + lane + 64*k8] = make_float4(t[s][2*k8].x, t[s][2*k8].y,
                                                     t[s][2*k8+1].x, t[s][2*k8+1].y);
        });
    };

    // ---- load psi, intensity mean, nonlinear rotation -> t[s] (= cur) ----
    static_for<2>([&](auto sI) {
        constexpr int s = sI.value;
        const int sys = sysA + s;
        float pr[16], pq[16], al[16];
        if (isbf) {
            const unsigned short* bR = (const unsigned short*)psi_r + (size_t)sys*1024 + lane*16;
            const unsigned short* bI = (const unsigned short*)psi_i + (size_t)sys*1024 + lane*16;
            const unsigned short* bA = (const unsigned short*)alpha  + lane*16;
            static_for<2>([&](auto hI) {
                constexpr int h = hI.value;
                uint4 a = ((const uint4*)bR)[h];
                uint4 bb = ((const uint4*)bI)[h];
                uint4 c = ((const uint4*)bA)[h];
                pr[h*8+0]=bf2f(a.x&0xFFFFu); pr[h*8+1]=bf2f(a.x>>16);
                pr[h*8+2]=bf2f(a.y&0xFFFFu); pr[h*8+3]=bf2f(a.y>>16);
                pr[h*8+4]=bf2f(a.z&0xFFFFu); pr[h*8+5]=bf2f(a.z>>16);
                pr[h*8+6]=bf2f(a.w&0xFFFFu); pr[h*8+7]=bf2f(a.w>>16);
                pq[h*8+0]=bf2f(bb.x&0xFFFFu); pq[h*8+1]=bf2f(bb.x>>16);
                pq[h*8+2]=bf2f(bb.y&0xFFFFu); pq[h*8+3]=bf2f(bb.y>>16);
                pq[h*8+4]=bf2f(bb.z&0xFFFFu); pq[h*8+5]=bf2f(bb.z>>16);
                pq[h*8+6]=bf2f(bb.w&0xFFFFu); pq[h*8+7]=bf2f(bb.w>>16);
                al[h*8+0]=bf2f(c.x&0xFFFFu); al[h*8+1]=bf2f(c.x>>16);
                al[h*8+2]=bf2f(c.y&0xFFFFu); al[h*8+3]=bf2f(c.y>>16);
                al[h*8+4]=bf2f(c.z&0xFFFFu); al[h*8+5]=bf2f(c.z>>16);
                al[h*8+6]=bf2f(c.w&0xFFFFu); al[h*8+7]=bf2f(c.w>>16);
            });
        } else {
            const float* fR = (const float*)psi_r + (size_t)sys*1024 + lane*16;
            const float* fI = (const float*)psi_i + (size_t)sys*1024 + lane*16;
            const float* fA = (const float*)alpha  + lane*16;
            static_for<4>([&](auto hI) {
                constexpr int h = hI.value;
                float4 a = ((const float4*)fR)[h];
                float4 bb = ((const float4*)fI)[h];
                float4 c = ((const float4*)fA)[h];
                pr[4*h]=a.x; pr[4*h+1]=a.y; pr[4*h+2]=a.z; pr[4*h+3]=a.w;
                pq[4*h]=bb.x; pq[4*h+1]=bb.y; pq[4*h+2]=bb.z; pq[4*h+3]=bb.w;
                al[4*h]=c.x; al[4*h+1]=c.y; al[4*h+2]=c.z; al[4*h+3]=c.w;
            });
        }

        float ssum = 0.f;
        #pragma unroll
        for (int k = 0; k < 16; ++k) ssum += pr[k]*pr[k] + pq[k]*pq[k];
        #pragma unroll
        for (int off = 32; off; off >>= 1) ssum += __shfl_xor(ssum, off, 64);
        const float inv = 1.f / (ssum * (1.f/1024.f) + 1e-8f);

        static_for<16>([&](auto kI) {
            constexpr int k = kI.value;
            float inten = (pr[k]*pr[k] + pq[k]*pq[k]) * inv;
            float ph = al[k] * inten;
            float cc = __cosf(ph), sn = __sinf(ph);
            t[s][k].x = pr[k]*cc - pq[k]*sn;
            t[s][k].y = pr[k]*sn + pq[k]*cc;
        });
        ldswrite(sI);
    });

    // Merged dual-system stencil: acc[s] = (h*H) t[s]. Own quads (g 10..17)
    // come from t registers; halo from LDS. Per-g, the two systems' loads and
    // 64 FMAs interleave -> each read's latency hides under the other stream.
    auto stencil2 = [&]() {
        static_for<2>([&](auto sI) {
            static_for<16>([&](auto kI) {
                acc[sI.value][kI.value].x = 0.f;
                acc[sI.value][kI.value].y = 0.f;
            });
        });
        static_for<28>([&](auto gI) {
            constexpr int g = gI.value;
            v2f eA0, eA1, eB0, eB1;
            if constexpr (g >= 10 && g <= 17) {
                eA0 = t[0][2*(g-10)];  eA1 = t[0][2*(g-10)+1];
                eB0 = t[1][2*(g-10)];  eB1 = t[1][2*(g-10)+1];
            } else {
                float4 qA = lds4[      rw[gslot(g)] + 64*gsub(g)];
                float4 qB = lds4[512 + rw[gslot(g)] + 64*gsub(g)];
                eA0.x = qA.x; eA0.y = qA.y;  eA1.x = qA.z; eA1.y = qA.w;
                eB0.x = qB.x; eB0.y = qB.y;  eB1.x = qB.z; eB1.y = qB.w;
            }
            static_for<16>([&](auto kI) {
                constexpr int k = kI.value;
                // window point j covers d = 16L-20+j ; tap distance = j-20-k
                constexpr int id0 = cidx(2*g     - 20 - k);
                constexpr int id1 = cidx(2*g + 1 - 20 - k);
                if constexpr (id0 >= 0) {
                    acc[0][k] += cs[id0] * eA0;
                    acc[1][k] += cs[id0] * eB0;
                }
                if constexpr (id1 >= 0) {
                    acc[0][k] += cs[id1] * eA1;
                    acc[1][k] += cs[id1] * eB1;
                }
            });
        });
    };

    // rhs b = (I - i*h*H) rot : b_r = rot_r + hH(rot_i) ; b_i = rot_i - hH(rot_r)
    stencil2();
    static_for<2>([&](auto sI) {
        constexpr int s = sI.value;
        static_for<16>([&](auto kI) {
            constexpr int k = kI.value;
            b[s][k].x = t[s][k].x + acc[s][k].y;
            b[s][k].y = t[s][k].y - acc[s][k].x;
        });
        static_for<16>([&](auto kI) { t[s][kI.value] = b[s][kI.value]; });
        ldswrite(sI);   // t0 = b
    });

    // Horner: t <- b - i*h*H t  ==> t_r = b_r + hH(t_i), t_i = b_i - hH(t_r)
    #pragma unroll 1
    for (int itn = 0; itn < KSTEPS; ++itn) {
        stencil2();
        static_for<2>([&](auto sI) {
            constexpr int s = sI.value;
            static_for<16>([&](auto kI) {
                constexpr int k = kI.value;
                t[s][k].x = b[s][k].x + acc[s][k].y;
                t[s][k].y = b[s][k].y - acc[s][k].x;
            });
        });
        if (itn != KSTEPS - 1) {
            ldswrite(std::integral_constant<int,0>{});
            ldswrite(std::integral_constant<int,1>{});
        }
    }

    // ---- store interleaved (r,i) pairs: 32 contiguous values at 32L ----
    static_for<2>([&](auto sI) {
        constexpr int s = sI.value;
        const int sys = sysA + s;
        if (isbf) {
            unsigned short* po = (unsigned short*)out + (size_t)sys*2048 + lane*32;
            uint4* po4 = (uint4*)po;
            static_for<4>([&](auto hI) {
                constexpr int h = hI.value;
                uint4 v;
                v.x = f2bf(t[s][4*h+0].x) | (f2bf(t[s][4*h+0].y) << 16);
                v.y = f2bf(t[s][4*h+1].x) | (f2bf(t[s][4*h+1].y) << 16);
                v.z = f2bf(t[s][4*h+2].x) | (f2bf(t[s][4*h+2].y) << 16);
                v.w = f2bf(t[s][4*h+3].x) | (f2bf(t[s][4*h+3].y) << 16);
                po4[h] = v;
            });
        } else {
            float* po = (float*)out + (size_t)sys*2048 + lane*32;
            static_for<8>([&](auto kI) {
                constexpr int k8 = kI.value;
                *(float4*)(po + 4*k8) = make_float4(t[s][2*k8].x, t[s][2*k8].y,
                                                    t[s][2*k8+1].x, t[s][2*k8+1].y);
            });
        }
    });
}

extern "C" void kernel_launch(void* const* d_in, const int* in_sizes, int n_in,
                              void* d_out, int out_size, void* d_ws, size_t ws_size,
                              hipStream_t stream)
{
    (void)in_sizes; (void)n_in; (void)out_size; (void)d_ws; (void)ws_size;
    cayley_main<<<dim3(8192), dim3(64), 0, stream>>>(d_in[0], d_in[1], d_in[2], d_in[3],
                                                     d_out);
}

// Round 7
// 279.345 us; speedup vs baseline: 1.0600x; 1.0600x over previous
//
#include <hip/hip_runtime.h>
#include <utility>

typedef float v2f __attribute__((ext_vector_type(2)));

#define HDT 0.05f      // dt/2
#define KSTEPS 5       // Horner order: worst-case rel err 0.33^6 ~ 1.3e-3 << bf16 ULP

template <int N> using ic = std::integral_constant<int, N>;

__device__ __forceinline__ float bf2f(unsigned int u) {
    return __uint_as_float(u << 16);
}
__device__ __forceinline__ unsigned int f2bf(float x) {
    unsigned int b = __float_as_uint(x);
    return (b + 0x7FFFu + ((b >> 16) & 1u)) >> 16;   // RNE
}
__device__ __forceinline__ float rfl(float x) {
    return __int_as_float(__builtin_amdgcn_readfirstlane(__float_as_int(x)));
}

// compile-time for: f(integral_constant<int,I>) for I in [0,N)
template <int... Is, class F>
__device__ __forceinline__ void static_for_impl(std::integer_sequence<int, Is...>, F&& f) {
    (f(std::integral_constant<int, Is>{}), ...);
}
template <int N, class F>
__device__ __forceinline__ void static_for(F&& f) {
    static_for_impl(std::make_integer_sequence<int, N>{}, (F&&)f);
}

// stencil coefficient slot for signed distance d (compile-time)
__host__ __device__ constexpr int cidx(int d) {
    int a = d < 0 ? -d : d;
    return (a==0)?0:(a==1)?1:(a==2)?2:(a==3)?3:(a==4)?4:(a==5)?5:(a==6)?6:
           (a==8)?7:(a==10)?8:(a==12)?9:(a==16)?10:(a==20)?11:-1;
}

// Transposed LDS layout (round-4, measured ZERO bank conflicts):
// quad qd lives at lds4[(qd&7)*64 + (qd>>3)].
// window quad g (qd=8L-10+g): row=(L+c)&63 with c=floor((g-10)/8), sub=(g+6)&7.
// 5 row registers (c=-2..+2), all read offsets are compile-time immediates.
__host__ __device__ constexpr int gslot(int g) {
    return (g < 2) ? 0 : (g < 10) ? 1 : (g < 18) ? 2 : (g < 26) ? 3 : 4;
}
__host__ __device__ constexpr int gsub(int g) { return (g + 6) & 7; }

// One wave == one block == one system; LDS wave-private, no barriers.
// This round: LDS holds SWAPPED pairs (e.y, e.x), so each complex tap
//   p.x += cs*e.y ; p.y -= cs*e.x
// is one 2-wide vector FMA  p += (cs,-cs) * e_swapped  -> compiler ISel
// emits v_pk_fma_f32 (full-rate packed FP32 on CDNA4: 157.3 TF = 2x scalar).
// First tap of point k is always j==k (d=-20) -> init form p[k] = base[k] + c*es
// (no acc zero-init, no epilogue adds; rhs and Horner share one fused apply).
// All 28 window quads come from LDS -> the Horner loop has ONE code instance
// and the fresh iterate is never on the stencil's critical path (round-5 lesson).
__global__ __launch_bounds__(64)
void cayley_main(const void* __restrict__ psi_r, const void* __restrict__ psi_i,
                 const void* __restrict__ alpha, const void* __restrict__ ham_w,
                 void* __restrict__ out)
{
    // 1 system/block * 512 quads (float4 = 2 complex pts, swapped) = 8 KB
    __shared__ float4 lds4[512];

    const int lane = threadIdx.x;      // 0..63
    const int sys  = blockIdx.x;       // [0, 16384)

    // ---- inline dtype probe: bf16 data's low-16 bits look like bf16 ----
    unsigned int w0 = ((const unsigned int*)psi_r)[lane];
    unsigned int ex = (w0 >> 7) & 0xFFu;
    unsigned long long bm = __ballot(ex >= 0x78u && ex <= 0x82u);
    const bool isbf = __builtin_popcountll(bm) > 32;

    // ---- combined stencil coefficients (h-scaled), packed (c, -c) ----
    float hw[15];
    if (isbf) {
        const unsigned short* p = (const unsigned short*)ham_w;
        #pragma unroll
        for (int i = 0; i < 15; ++i) hw[i] = bf2f((unsigned int)p[i]);
    } else {
        const float* p = (const float*)ham_w;
        #pragma unroll
        for (int i = 0; i < 15; ++i) hw[i] = p[i];
    }
    v2f cspv[12];
    {
        float s = 0.f;
        #pragma unroll
        for (int i = 0; i < 15; ++i) s += hw[i];
        auto mk = [&](float c) { v2f r; float u = rfl(c); r.x = u; r.y = -u; return r; };
        cspv[0]  = mk( 2.f*HDT*s);                       // center
        cspv[1]  = mk(-HDT* hw[0]);                      // off 1
        cspv[2]  = mk(-HDT*(hw[1]+hw[5]));               // off 2
        cspv[3]  = mk(-HDT* hw[2]);                      // off 3
        cspv[4]  = mk(-HDT*(hw[3]+hw[6]+hw[10]));        // off 4
        cspv[5]  = mk(-HDT* hw[4]);                      // off 5
        cspv[6]  = mk(-HDT* hw[7]);                      // off 6
        cspv[7]  = mk(-HDT*(hw[8]+hw[11]));              // off 8
        cspv[8]  = mk(-HDT* hw[9]);                      // off 10
        cspv[9]  = mk(-HDT* hw[12]);                     // off 12
        cspv[10] = mk(-HDT* hw[13]);                     // off 16
        cspv[11] = mk(-HDT* hw[14]);                     // off 20
    }

    // ---- row registers for the transposed LDS layout ----
    int rw[5];
    rw[0] = (lane - 2) & 63;   // c = -2  (g 0..1)
    rw[1] = (lane - 1) & 63;   // c = -1  (g 2..9)
    rw[2] = lane;              // c =  0  (g 10..17, own quads)
    rw[3] = (lane + 1) & 63;   // c = +1  (g 18..25)
    rw[4] = (lane + 2) & 63;   // c = +2  (g 26..27)

    // ---- load psi (16 points per lane) and alpha ----
    float pr[16], pq[16], al[16];
    if (isbf) {
        const unsigned short* bR = (const unsigned short*)psi_r + (size_t)sys*1024 + lane*16;
        const unsigned short* bI = (const unsigned short*)psi_i + (size_t)sys*1024 + lane*16;
        const unsigned short* bA = (const unsigned short*)alpha  + lane*16;
        static_for<2>([&](auto hI) {
            constexpr int h = hI.value;
            uint4 a = ((const uint4*)bR)[h];
            uint4 b = ((const uint4*)bI)[h];
            uint4 c = ((const uint4*)bA)[h];
            pr[h*8+0]=bf2f(a.x&0xFFFFu); pr[h*8+1]=bf2f(a.x>>16);
            pr[h*8+2]=bf2f(a.y&0xFFFFu); pr[h*8+3]=bf2f(a.y>>16);
            pr[h*8+4]=bf2f(a.z&0xFFFFu); pr[h*8+5]=bf2f(a.z>>16);
            pr[h*8+6]=bf2f(a.w&0xFFFFu); pr[h*8+7]=bf2f(a.w>>16);
            pq[h*8+0]=bf2f(b.x&0xFFFFu); pq[h*8+1]=bf2f(b.x>>16);
            pq[h*8+2]=bf2f(b.y&0xFFFFu); pq[h*8+3]=bf2f(b.y>>16);
            pq[h*8+4]=bf2f(b.z&0xFFFFu); pq[h*8+5]=bf2f(b.z>>16);
            pq[h*8+6]=bf2f(b.w&0xFFFFu); pq[h*8+7]=bf2f(b.w>>16);
            al[h*8+0]=bf2f(c.x&0xFFFFu); al[h*8+1]=bf2f(c.x>>16);
            al[h*8+2]=bf2f(c.y&0xFFFFu); al[h*8+3]=bf2f(c.y>>16);
            al[h*8+4]=bf2f(c.z&0xFFFFu); al[h*8+5]=bf2f(c.z>>16);
            al[h*8+6]=bf2f(c.w&0xFFFFu); al[h*8+7]=bf2f(c.w>>16);
        });
    } else {
        const float* fR = (const float*)psi_r + (size_t)sys*1024 + lane*16;
        const float* fI = (const float*)psi_i + (size_t)sys*1024 + lane*16;
        const float* fA = (const float*)alpha  + lane*16;
        static_for<4>([&](auto hI) {
            constexpr int h = hI.value;
            float4 a = ((const float4*)fR)[h];
            float4 b = ((const float4*)fI)[h];
            float4 c = ((const float4*)fA)[h];
            pr[4*h]=a.x; pr[4*h+1]=a.y; pr[4*h+2]=a.z; pr[4*h+3]=a.w;
            pq[4*h]=b.x; pq[4*h+1]=b.y; pq[4*h+2]=b.z; pq[4*h+3]=b.w;
            al[4*h]=c.x; al[4*h+1]=c.y; al[4*h+2]=c.z; al[4*h+3]=c.w;
        });
    }

    // ---- intensity mean (wave reduction; one wave == one system) ----
    float ssum = 0.f;
    #pragma unroll
    for (int k = 0; k < 16; ++k) ssum += pr[k]*pr[k] + pq[k]*pq[k];
    #pragma unroll
    for (int off = 32; off; off >>= 1) ssum += __shfl_xor(ssum, off, 64);
    const float inv = 1.f / (ssum * (1.f/1024.f) + 1e-8f);

    // ---- nonlinear phase rotation -> t (= cur) ----
    v2f t[16], bv[16];
    static_for<16>([&](auto kI) {
        constexpr int k = kI.value;
        float inten = (pr[k]*pr[k] + pq[k]*pq[k]) * inv;
        float ph = al[k] * inten;
        float cc = __cosf(ph), sn = __sinf(ph);
        t[k].x = pr[k]*cc - pq[k]*sn;
        t[k].y = pr[k]*sn + pq[k]*cc;
    });

    // readers/writers (constexpr-indexed, never take array addresses -> SROA-safe)
    auto rdT = [&](auto kI) { return t[kI.value]; };
    auto rdV = [&](auto kI) { return bv[kI.value]; };
    auto wrT = [&](auto kI, v2f v) { t[kI.value] = v; };
    auto wrV = [&](auto kI, v2f v) { bv[kI.value] = v; };

    // LDS write: swapped pairs (y,x) so taps need no half-swap modifier
    auto wrLds = [&](auto rd) {
        static_for<8>([&](auto kI) {
            constexpr int k8 = kI.value;
            v2f a = rd(ic<2*k8>{}), b = rd(ic<2*k8+1>{});
            lds4[lane + 64*k8] = make_float4(a.y, a.x, b.y, b.x);
        });
    };

    // fused apply: out[k] = base[k] + i-rot(hH src), src = LDS (swapped).
    // Per (tap,point): p += (cs,-cs) * es  -> one v_pk_fma_f32.
    // First tap of point k is j==k (d=-20): init form p = base + c*es.
    auto apply = [&](auto rdBase, auto wrOut) {
        v2f p[16];
        static_for<28>([&](auto gI) {
            constexpr int g = gI.value;
            float4 q = lds4[rw[gslot(g)] + 64*gsub(g)];
            v2f es0; es0.x = q.x; es0.y = q.y;   // = (e0.y, e0.x)
            v2f es1; es1.x = q.z; es1.y = q.w;   // = (e1.y, e1.x)
            static_for<2>([&](auto eI) {
                constexpr int el = eI.value;
                constexpr int j = 2*g + el;
                v2f es;
                if constexpr (el == 0) es = es0; else es = es1;
                static_for<16>([&](auto kI) {
                    constexpr int k = kI.value;
                    constexpr int id = cidx(j - 20 - k);
                    if constexpr (id >= 0) {
                        if constexpr (j == k) p[k] = rdBase(kI) + cspv[id] * es;
                        else                  p[k] += cspv[id] * es;
                    }
                });
            });
        });
        static_for<16>([&](auto kI) { wrOut(kI, p[kI.value]); });
    };

    // ---- rhs: bv = (I - i*h*H) cur ; then Horner t <- bv - i*h*H t ----
    wrLds(rdT);              // LDS = cur (swapped)
    apply(rdT, wrV);         // bv = rhs
    static_for<16>([&](auto kI) { t[kI.value] = bv[kI.value]; });   // t0 = bv
    #pragma unroll 1
    for (int itn = 0; itn < KSTEPS; ++itn) {
        wrLds(rdT);          // LDS = t (swapped)
        apply(rdV, wrT);     // t = bv + i-rot(hH t)
    }

    // ---- store interleaved (r,i) pairs: 32 contiguous values at 32L ----
    if (isbf) {
        unsigned short* po = (unsigned short*)out + (size_t)sys*2048 + lane*32;
        uint4* po4 = (uint4*)po;
        static_for<4>([&](auto hI) {
            constexpr int h = hI.value;
            uint4 v;
            v.x = f2bf(t[4*h+0].x) | (f2bf(t[4*h+0].y) << 16);
            v.y = f2bf(t[4*h+1].x) | (f2bf(t[4*h+1].y) << 16);
            v.z = f2bf(t[4*h+2].x) | (f2bf(t[4*h+2].y) << 16);
            v.w = f2bf(t[4*h+3].x) | (f2bf(t[4*h+3].y) << 16);
            po4[h] = v;
        });
    } else {
        float* po = (float*)out + (size_t)sys*2048 + lane*32;
        static_for<8>([&](auto kI) {
            constexpr int k8 = kI.value;
            *(float4*)(po + 4*k8) = make_float4(t[2*k8].x, t[2*k8].y,
                                                t[2*k8+1].x, t[2*k8+1].y);
        });
    }
}

extern "C" void kernel_launch(void* const* d_in, const int* in_sizes, int n_in,
                              void* d_out, int out_size, void* d_ws, size_t ws_size,
                              hipStream_t stream)
{
    (void)in_sizes; (void)n_in; (void)out_size; (void)d_ws; (void)ws_size;
    cayley_main<<<dim3(16384), dim3(64), 0, stream>>>(d_in[0], d_in[1], d_in[2], d_in[3],
                                                      d_out);
}

// Round 8
// 271.348 us; speedup vs baseline: 1.0912x; 1.0295x over previous
//
#include <hip/hip_runtime.h>
#include <utility>

typedef float v2f __attribute__((ext_vector_type(2)));

#define HDT 0.05f      // dt/2
#define KSTEPS 5       // Horner order: worst-case rel err 0.33^6 ~ 1.3e-3 << bf16 ULP

template <int N> using ic = std::integral_constant<int, N>;

__device__ __forceinline__ float bf2f(unsigned int u) {
    return __uint_as_float(u << 16);
}
__device__ __forceinline__ unsigned int f2bf(float x) {
    unsigned int b = __float_as_uint(x);
    return (b + 0x7FFFu + ((b >> 16) & 1u)) >> 16;   // RNE
}
__device__ __forceinline__ float rfl(float x) {
    return __int_as_float(__builtin_amdgcn_readfirstlane(__float_as_int(x)));
}

// compile-time for: f(integral_constant<int,I>) for I in [0,N)
template <int... Is, class F>
__device__ __forceinline__ void static_for_impl(std::integer_sequence<int, Is...>, F&& f) {
    (f(std::integral_constant<int, Is>{}), ...);
}
template <int N, class F>
__device__ __forceinline__ void static_for(F&& f) {
    static_for_impl(std::make_integer_sequence<int, N>{}, (F&&)f);
}

// stencil coefficient slot for signed distance d (compile-time)
__host__ __device__ constexpr int cidx(int d) {
    int a = d < 0 ? -d : d;
    return (a==0)?0:(a==1)?1:(a==2)?2:(a==3)?3:(a==4)?4:(a==5)?5:(a==6)?6:
           (a==8)?7:(a==10)?8:(a==12)?9:(a==16)?10:(a==20)?11:-1;
}

// Transposed LDS layout (round-4, measured ZERO bank conflicts):
// quad qd lives at lds4[(qd&7)*64 + (qd>>3)].
// Own quads (g 10..17) come from registers; halo quads via 4 row regs:
__host__ __device__ constexpr int gslot(int g) {   // g -> row-register slot
    return (g < 2) ? 0 : (g < 10) ? 1 : (g < 26) ? 2 : 3;   // c = -2,-1,+1,+2
}
__host__ __device__ constexpr int gsub(int g) { return (g + 6) & 7; }

// One wave == one block == one system; LDS wave-private, no barriers.
//
// Packed-FP32 taps with PARITY ALTERNATION (no swap instructions ever):
//   normal-space tap: out.x += s*e.y ; out.y -= s*e.x
//   input NORMAL  -> accumulate SWAPPED out:  q += (-s,+s) * e      (cfA)
//   input SWAPPED -> accumulate NORMAL  out:  p += (+s,-s) * es     (cfB)
// Each apply flips the iterate's representation; LDS stores register order.
// Every tap is ONE v_pk_fma_f32 via __builtin_elementwise_fma (llvm.fma.v2f32,
// selected as packed on gfx950 = 2x scalar FP32 rate). The first tap of point
// k (j==k, d=-20) is the init: packed when base parity matches output parity,
// else 2 scalar FMAs reading crossed base components (no swap needed).
__global__ __launch_bounds__(64)
void cayley_main(const void* __restrict__ psi_r, const void* __restrict__ psi_i,
                 const void* __restrict__ alpha, const void* __restrict__ ham_w,
                 void* __restrict__ out)
{
    // 1 system/block * 512 quads (float4 = 2 complex pts) = 8 KB
    __shared__ float4 lds4[512];

    const int lane = threadIdx.x;      // 0..63
    const int sys  = blockIdx.x;       // [0, 16384)

    // ---- inline dtype probe: bf16 data's low-16 bits look like bf16 ----
    unsigned int w0 = ((const unsigned int*)psi_r)[lane];
    unsigned int ex = (w0 >> 7) & 0xFFu;
    unsigned long long bm = __ballot(ex >= 0x78u && ex <= 0x82u);
    const bool isbf = __builtin_popcountll(bm) > 32;

    // ---- combined stencil coefficients (h-scaled), both parities ----
    float hw[15];
    if (isbf) {
        const unsigned short* p = (const unsigned short*)ham_w;
        #pragma unroll
        for (int i = 0; i < 15; ++i) hw[i] = bf2f((unsigned int)p[i]);
    } else {
        const float* p = (const float*)ham_w;
        #pragma unroll
        for (int i = 0; i < 15; ++i) hw[i] = p[i];
    }
    v2f cfA[12];   // (-s, +s): input NORMAL  -> output SWAPPED
    v2f cfB[12];   // (+s, -s): input SWAPPED -> output NORMAL
    {
        float s = 0.f;
        #pragma unroll
        for (int i = 0; i < 15; ++i) s += hw[i];
        float sc[12];
        sc[0]  = rfl( 2.f*HDT*s);                       // center
        sc[1]  = rfl(-HDT* hw[0]);                      // off 1
        sc[2]  = rfl(-HDT*(hw[1]+hw[5]));               // off 2
        sc[3]  = rfl(-HDT* hw[2]);                      // off 3
        sc[4]  = rfl(-HDT*(hw[3]+hw[6]+hw[10]));        // off 4
        sc[5]  = rfl(-HDT* hw[4]);                      // off 5
        sc[6]  = rfl(-HDT* hw[7]);                      // off 6
        sc[7]  = rfl(-HDT*(hw[8]+hw[11]));              // off 8
        sc[8]  = rfl(-HDT* hw[9]);                      // off 10
        sc[9]  = rfl(-HDT* hw[12]);                     // off 12
        sc[10] = rfl(-HDT* hw[13]);                     // off 16
        sc[11] = rfl(-HDT* hw[14]);                     // off 20
        #pragma unroll
        for (int i = 0; i < 12; ++i) {
            cfA[i].x = -sc[i]; cfA[i].y =  sc[i];
            cfB[i].x =  sc[i]; cfB[i].y = -sc[i];
        }
    }

    // ---- row registers for the transposed LDS layout ----
    int rw[4];
    rw[0] = (lane - 2) & 63;   // c = -2  (g 0..1)
    rw[1] = (lane - 1) & 63;   // c = -1  (g 2..9)
    rw[2] = (lane + 1) & 63;   // c = +1  (g 18..25)
    rw[3] = (lane + 2) & 63;   // c = +2  (g 26..27)

    // ---- load psi (16 points per lane) and alpha ----
    float pr[16], pq[16], al[16];
    if (isbf) {
        const unsigned short* bR = (const unsigned short*)psi_r + (size_t)sys*1024 + lane*16;
        const unsigned short* bI = (const unsigned short*)psi_i + (size_t)sys*1024 + lane*16;
        const unsigned short* bA = (const unsigned short*)alpha  + lane*16;
        static_for<2>([&](auto hI) {
            constexpr int h = hI.value;
            uint4 a = ((const uint4*)bR)[h];
            uint4 b = ((const uint4*)bI)[h];
            uint4 c = ((const uint4*)bA)[h];
            pr[h*8+0]=bf2f(a.x&0xFFFFu); pr[h*8+1]=bf2f(a.x>>16);
            pr[h*8+2]=bf2f(a.y&0xFFFFu); pr[h*8+3]=bf2f(a.y>>16);
            pr[h*8+4]=bf2f(a.z&0xFFFFu); pr[h*8+5]=bf2f(a.z>>16);
            pr[h*8+6]=bf2f(a.w&0xFFFFu); pr[h*8+7]=bf2f(a.w>>16);
            pq[h*8+0]=bf2f(b.x&0xFFFFu); pq[h*8+1]=bf2f(b.x>>16);
            pq[h*8+2]=bf2f(b.y&0xFFFFu); pq[h*8+3]=bf2f(b.y>>16);
            pq[h*8+4]=bf2f(b.z&0xFFFFu); pq[h*8+5]=bf2f(b.z>>16);
            pq[h*8+6]=bf2f(b.w&0xFFFFu); pq[h*8+7]=bf2f(b.w>>16);
            al[h*8+0]=bf2f(c.x&0xFFFFu); al[h*8+1]=bf2f(c.x>>16);
            al[h*8+2]=bf2f(c.y&0xFFFFu); al[h*8+3]=bf2f(c.y>>16);
            al[h*8+4]=bf2f(c.z&0xFFFFu); al[h*8+5]=bf2f(c.z>>16);
            al[h*8+6]=bf2f(c.w&0xFFFFu); al[h*8+7]=bf2f(c.w>>16);
        });
    } else {
        const float* fR = (const float*)psi_r + (size_t)sys*1024 + lane*16;
        const float* fI = (const float*)psi_i + (size_t)sys*1024 + lane*16;
        const float* fA = (const float*)alpha  + lane*16;
        static_for<4>([&](auto hI) {
            constexpr int h = hI.value;
            float4 a = ((const float4*)fR)[h];
            float4 b = ((const float4*)fI)[h];
            float4 c = ((const float4*)fA)[h];
            pr[4*h]=a.x; pr[4*h+1]=a.y; pr[4*h+2]=a.z; pr[4*h+3]=a.w;
            pq[4*h]=b.x; pq[4*h+1]=b.y; pq[4*h+2]=b.z; pq[4*h+3]=b.w;
            al[4*h]=c.x; al[4*h+1]=c.y; al[4*h+2]=c.z; al[4*h+3]=c.w;
        });
    }

    // ---- intensity mean (wave reduction; one wave == one system) ----
    float ssum = 0.f;
    #pragma unroll
    for (int k = 0; k < 16; ++k) ssum += pr[k]*pr[k] + pq[k]*pq[k];
    #pragma unroll
    for (int off = 32; off; off >>= 1) ssum += __shfl_xor(ssum, off, 64);
    const float inv = 1.f / (ssum * (1.f/1024.f) + 1e-8f);

    // ---- nonlinear phase rotation -> t (= cur, NORMAL parity) ----
    v2f t[16], bv[16];
    static_for<16>([&](auto kI) {
        constexpr int k = kI.value;
        float inten = (pr[k]*pr[k] + pq[k]*pq[k]) * inv;
        float ph = al[k] * inten;
        float cc = __cosf(ph), sn = __sinf(ph);
        t[k].x = pr[k]*cc - pq[k]*sn;
        t[k].y = pr[k]*sn + pq[k]*cc;
    });

    // readers/writers (constexpr-indexed, never take array addresses -> SROA-safe)
    auto rdT = [&](auto kI) { return t[kI.value]; };
    auto rdV = [&](auto kI) { return bv[kI.value]; };
    auto wrT = [&](auto kI, v2f v) { t[kI.value] = v; };
    auto wrV = [&](auto kI, v2f v) { bv[kI.value] = v; };

    // LDS write: raw register order (parity-preserving, free)
    auto wrLds = [&](auto rd) {
        static_for<8>([&](auto kI) {
            constexpr int k8 = kI.value;
            v2f a = rd(ic<2*k8>{}), b = rd(ic<2*k8+1>{});
            lds4[lane + 64*k8] = make_float4(a.x, a.y, b.x, b.y);
        });
    };

    // fused apply: out[k] = (base + J(hH src)) in the OPPOSITE parity of src.
    //  swIn = 0: src NORMAL,  out SWAPPED, cf = cfA
    //  swIn = 1: src SWAPPED, out NORMAL,  cf = cfB
    //  matched = (base parity == out parity): packed init; else crossed scalar init.
    auto apply = [&](auto swInI, auto matchedI, auto rdSrc, auto rdBase, auto wrOut) {
        constexpr bool swIn = decltype(swInI)::value;
        constexpr bool matched = decltype(matchedI)::value;
        v2f p[16];
        static_for<28>([&](auto gI) {
            constexpr int g = gI.value;
            v2f e0, e1;
            if constexpr (g >= 10 && g <= 17) {
                e0 = rdSrc(ic<2*(g-10)>{});
                e1 = rdSrc(ic<2*(g-10)+1>{});
            } else {
                float4 q = lds4[rw[gslot(g)] + 64*gsub(g)];
                e0.x = q.x; e0.y = q.y;
                e1.x = q.z; e1.y = q.w;
            }
            static_for<2>([&](auto eI) {
                constexpr int el = eI.value;
                constexpr int j = 2*g + el;
                v2f e;
                if constexpr (el == 0) e = e0; else e = e1;
                static_for<16>([&](auto kI) {
                    constexpr int k = kI.value;
                    constexpr int id = cidx(j - 20 - k);
                    if constexpr (id >= 0) {
                        v2f cf;
                        if constexpr (swIn) cf = cfB[id]; else cf = cfA[id];
                        if constexpr (j == k) {
                            v2f base = rdBase(kI);
                            if constexpr (matched) {
                                p[k] = __builtin_elementwise_fma(cf, e, base);
                            } else {
                                // crossed init: base parity != out parity
                                p[k].x = __builtin_fmaf(cf.x, e.x, base.y);
                                p[k].y = __builtin_fmaf(cf.y, e.y, base.x);
                            }
                        } else {
                            p[k] = __builtin_elementwise_fma(cf, e, p[k]);
                        }
                    }
                });
            });
        });
        static_for<16>([&](auto kI) { wrOut(kI, p[kI.value]); });
    };

    // ---- schedule (parity in comments) ----
    // A0: cur(N) -> bv(S), base cur(N) vs out S -> crossed
    wrLds(rdT);  apply(ic<0>{}, ic<0>{}, rdT, rdT, wrV);
    // A1: bv(S) -> t(N), base bv(S) vs out N -> crossed
    wrLds(rdV);  apply(ic<1>{}, ic<0>{}, rdV, rdV, wrT);
    // A2: t(N) -> t(S), base bv(S) -> matched
    wrLds(rdT);  apply(ic<0>{}, ic<1>{}, rdT, rdV, wrT);
    // A3: t(S) -> t(N), base bv(S) -> crossed
    wrLds(rdT);  apply(ic<1>{}, ic<0>{}, rdT, rdV, wrT);
    // A4: t(N) -> t(S), base bv(S) -> matched
    wrLds(rdT);  apply(ic<0>{}, ic<1>{}, rdT, rdV, wrT);
    // A5: t(S) -> t(N), base bv(S) -> crossed  (final iterate NORMAL)
    wrLds(rdT);  apply(ic<1>{}, ic<0>{}, rdT, rdV, wrT);

    // ---- store interleaved (r,i) pairs: 32 contiguous values at 32L ----
    if (isbf) {
        unsigned short* po = (unsigned short*)out + (size_t)sys*2048 + lane*32;
        uint4* po4 = (uint4*)po;
        static_for<4>([&](auto hI) {
            constexpr int h = hI.value;
            uint4 v;
            v.x = f2bf(t[4*h+0].x) | (f2bf(t[4*h+0].y) << 16);
            v.y = f2bf(t[4*h+1].x) | (f2bf(t[4*h+1].y) << 16);
            v.z = f2bf(t[4*h+2].x) | (f2bf(t[4*h+2].y) << 16);
            v.w = f2bf(t[4*h+3].x) | (f2bf(t[4*h+3].y) << 16);
            po4[h] = v;
        });
    } else {
        float* po = (float*)out + (size_t)sys*2048 + lane*32;
        static_for<8>([&](auto kI) {
            constexpr int k8 = kI.value;
            *(float4*)(po + 4*k8) = make_float4(t[2*k8].x, t[2*k8].y,
                                                t[2*k8+1].x, t[2*k8+1].y);
        });
    }
}

extern "C" void kernel_launch(void* const* d_in, const int* in_sizes, int n_in,
                              void* d_out, int out_size, void* d_ws, size_t ws_size,
                              hipStream_t stream)
{
    (void)in_sizes; (void)n_in; (void)out_size; (void)d_ws; (void)ws_size;
    cayley_main<<<dim3(16384), dim3(64), 0, stream>>>(d_in[0], d_in[1], d_in[2], d_in[3],
                                                      d_out);
}